// Round 18
// baseline (106.381 us; speedup 1.0000x reference)
//
#include <hip/hip_runtime.h>
#include <hip/hip_bf16.h>

// Problem dims: x[b=8, c=64, h=64, w=64, t=12] fp32
// x float offsets: b*3145728 + c*49152 + h*768 + w*12 + t
//
// Scratch inside d_out (floats), consumed before k_out overwrites d_out:
//   [4096, 4096+20*393216) : u[cq*5+dh][m*12+t]  (20 planes, 31.4 MB)
#define U_OFF    4096
#define U_PLANE  393216   // floats per plane
// d_ws: p[m*12+t] (1.57 MB) + weff[c*25+tap] at float offset 393216
#define WS_WEFF_OFF 393216
#define WEFF_FALLBACK_OFF 0   // in d_out if ws too small

// ---------------------------------------------------------------------------
// K1: fold 1x1-conv (key half of w1) into the 5x5 conv weights.
__global__ __launch_bounds__(256) void k_prep(const float* __restrict__ w1,
                                              const float* __restrict__ w2,
                                              float* __restrict__ wdst) {
    int idx = blockIdx.x * 256 + threadIdx.x;
    if (idx >= 64 * 25) return;
    int cp = idx / 25, tap = idx % 25;
    float s = 0.f;
    for (int c = 0; c < 64; ++c)
        s = fmaf(w2[(64 + c) * 25 + tap], w1[(64 + c) * 64 + cp], s);
    wdst[cp * 25 + tap] = s;
}

// ---------------------------------------------------------------------------
// K2a (k_tap v9): the last untested design-matrix cell — float4 loads
// (4x fewer load instructions than R16; all 4 SIMDs share one L1/TA per CU)
// x t-complete threads (no cache-line splits) x 24 waves/CU x dh-factored.
// Thread per (m, tg, cq): 16 channels, 5 f4 loads each (dw-shifts +-3/+-6
// f4 = same lines, L1 hits), 5 f4 accumulators, wave-uniform s_load weights.
// Writes 20 partial planes u[cq*5+dh] (31 MB, L2/L3-resident).
__global__ __launch_bounds__(256) void k_tap(const float* __restrict__ x,
                                             const float* __restrict__ weff,
                                             float* __restrict__ u) {
    const int n     = blockIdx.x * 256 + threadIdx.x;   // 0..393215
    const int cq    = n / 98304;                        // block-uniform (384 blk/cq)
    const int inner = n - cq * 98304;                   // = b*12288 + local_n
    const int b     = inner / 12288;                    // block-uniform (48 blk/b)
    const int ln    = inner - b * 12288;                // h*192 + w*3 + tg
    const int w     = (ln / 3) & 63;

    // x base for this (b, h, w, tg), channel cq*16
    const float* xp = x + (size_t)b * 3145728 + (size_t)(cq * 16) * 49152
                        + (size_t)ln * 4;

    // w-edge predicates; clamped f4 offsets (units of floats)
    const bool ok0 = (w >= 2), ok1 = (w >= 1), ok3 = (w <= 62), ok4 = (w <= 61);
    const int  o0 = ok0 ? -24 : 0, o1 = ok1 ? -12 : 0;
    const int  o3 = ok3 ?  12 : 0, o4 = ok4 ?  24 : 0;

    float4 u0, u1, u2, u3, u4;
    u0.x=0.f;u0.y=0.f;u0.z=0.f;u0.w=0.f; u1=u0; u2=u0; u3=u0; u4=u0;

    const float* wbase = weff + cq * 16 * 25;
    const float4 zero = u0;

    for (int j = 0; j < 16; ++j) {
        const float* base = xp + (size_t)j * 49152;
        float4 x0 = *(const float4*)(base + o0);
        float4 x1 = *(const float4*)(base + o1);
        float4 x2 = *(const float4*)(base);
        float4 x3 = *(const float4*)(base + o3);
        float4 x4 = *(const float4*)(base + o4);
        if (!ok0) x0 = zero;
        if (!ok1) x1 = zero;
        if (!ok3) x3 = zero;
        if (!ok4) x4 = zero;

        const float* wg = wbase + j * 25;   // wave-uniform -> s_load
#pragma unroll
        for (int dh = 0; dh < 5; ++dh) {
            const float g0 = wg[dh * 5 + 0];
            const float g1 = wg[dh * 5 + 1];
            const float g2 = wg[dh * 5 + 2];
            const float g3 = wg[dh * 5 + 3];
            const float g4 = wg[dh * 5 + 4];
            float4* uacc = (dh == 0) ? &u0 : (dh == 1) ? &u1 : (dh == 2) ? &u2
                          : (dh == 3) ? &u3 : &u4;
            uacc->x = fmaf(g0, x0.x, uacc->x); uacc->y = fmaf(g0, x0.y, uacc->y);
            uacc->z = fmaf(g0, x0.z, uacc->z); uacc->w = fmaf(g0, x0.w, uacc->w);
            uacc->x = fmaf(g1, x1.x, uacc->x); uacc->y = fmaf(g1, x1.y, uacc->y);
            uacc->z = fmaf(g1, x1.z, uacc->z); uacc->w = fmaf(g1, x1.w, uacc->w);
            uacc->x = fmaf(g2, x2.x, uacc->x); uacc->y = fmaf(g2, x2.y, uacc->y);
            uacc->z = fmaf(g2, x2.z, uacc->z); uacc->w = fmaf(g2, x2.w, uacc->w);
            uacc->x = fmaf(g3, x3.x, uacc->x); uacc->y = fmaf(g3, x3.y, uacc->y);
            uacc->z = fmaf(g3, x3.z, uacc->z); uacc->w = fmaf(g3, x3.w, uacc->w);
            uacc->x = fmaf(g4, x4.x, uacc->x); uacc->y = fmaf(g4, x4.y, uacc->y);
            uacc->z = fmaf(g4, x4.z, uacc->z); uacc->w = fmaf(g4, x4.w, uacc->w);
        }
    }

    // writes: plane (cq*5+dh), offset inner*4 floats — coalesced f4
    float* ub = u + (size_t)(cq * 5) * U_PLANE + (size_t)inner * 4;
    *(float4*)(ub + (size_t)0 * U_PLANE) = u0;
    *(float4*)(ub + (size_t)1 * U_PLANE) = u1;
    *(float4*)(ub + (size_t)2 * U_PLANE) = u2;
    *(float4*)(ub + (size_t)3 * U_PLANE) = u3;
    *(float4*)(ub + (size_t)4 * U_PLANE) = u4;
}

// ---------------------------------------------------------------------------
// K2b (k_gather, 20-plane): A_k[m,t] = sum_{cq,dh} u[cq*5+dh][b,h+dh-2,w,t]
// (OOB dh skipped == zero-pad), softmax over t, write p. u is L2/L3-resident.
__global__ __launch_bounds__(256) void k_gather(const float* __restrict__ u,
                                                float* __restrict__ p) {
    const int tid  = threadIdx.x;
    const int m    = blockIdx.x * 64 + (tid >> 2);   // 0..32767
    const int q    = tid & 3;
    const int qq   = (q == 3) ? 2 : q;
    const int w    = m & 63;
    const int h    = (m >> 6) & 63;
    const int b    = m >> 12;

    float4 a; a.x = 0.f; a.y = 0.f; a.z = 0.f; a.w = 0.f;

#pragma unroll
    for (int dh = 0; dh < 5; ++dh) {
        const int hh = h + dh - 2;
        if ((unsigned)hh >= 64u) continue;           // block-uniform skip
        const size_t moff = (size_t)(((b * 64 + hh) * 64 + w)) * 12 + qq * 4;
#pragma unroll
        for (int cq = 0; cq < 4; ++cq) {
            float4 v = *(const float4*)(u + (size_t)(cq * 5 + dh) * U_PLANE + moff);
            a.x += v.x; a.y += v.y; a.z += v.z; a.w += v.w;
        }
    }

    float mx = fmaxf(fmaxf(a.x, a.y), fmaxf(a.z, a.w));
    mx = fmaxf(mx, __shfl_xor(mx, 1, 4));
    mx = fmaxf(mx, __shfl_xor(mx, 2, 4));

    float e0 = __expf(a.x - mx), e1 = __expf(a.y - mx);
    float e2 = __expf(a.z - mx), e3 = __expf(a.w - mx);
    const float s4 = e0 + e1 + e2 + e3;
    const float s0 = __shfl(s4, 0, 4);
    const float s1 = __shfl(s4, 1, 4);
    const float s2 = __shfl(s4, 2, 4);
    const float inv = 1.f / (s0 + s1 + s2);

    if (q < 3) {
        float4 o; o.x = e0 * inv; o.y = e1 * inv; o.z = e2 * inv; o.w = e3 * inv;
        *(float4*)(p + (size_t)m * 12 + q * 4) = o;
    }
}

// ---------------------------------------------------------------------------
// K4: out[b,c,h,w,s] = W1v · (sum_t p_t * x[:,t]) + b1v, broadcast over s.
// One block per (b,h): 512 threads = 64 w-lanes * 8 channel-groups.
// Proven ~34 us (near its 200MB roofline).
__global__ __launch_bounds__(512) void k_out(const float* __restrict__ x,
                                             const float* __restrict__ w1,
                                             const float* __restrict__ b1,
                                             const float* __restrict__ p,
                                             float* __restrict__ out) {
    __shared__ float lds[64 * 65];   // [w][c], padded -> conflict-free

    const int b  = blockIdx.x >> 6;
    const int h  = blockIdx.x & 63;
    const int w  = threadIdx.x & 63;
    const int cg = threadIdx.x >> 6;     // 0..7

    const float* pp = p + (size_t)((b * 64 + h) * 64 + w) * 12;
    float pv[12];
    {
        float4 t0 = *(const float4*)(pp);
        float4 t1 = *(const float4*)(pp + 4);
        float4 t2 = *(const float4*)(pp + 8);
        pv[0] = t0.x; pv[1] = t0.y; pv[2]  = t0.z; pv[3]  = t0.w;
        pv[4] = t1.x; pv[5] = t1.y; pv[6]  = t1.z; pv[7]  = t1.w;
        pv[8] = t2.x; pv[9] = t2.y; pv[10] = t2.z; pv[11] = t2.w;
    }

    const float* xb0 = x + ((size_t)(b * 64 + cg * 8) * 64 + h) * 768 + w * 12;
#pragma unroll
    for (int j = 0; j < 8; ++j) {
        const float* xp = xb0 + (size_t)j * 49152;
        float4 u0 = *(const float4*)(xp);
        float4 u1 = *(const float4*)(xp + 4);
        float4 u2 = *(const float4*)(xp + 8);
        float s = 0.f;
        s = fmaf(pv[0], u0.x, s);  s = fmaf(pv[1], u0.y, s);
        s = fmaf(pv[2], u0.z, s);  s = fmaf(pv[3], u0.w, s);
        s = fmaf(pv[4], u1.x, s);  s = fmaf(pv[5], u1.y, s);
        s = fmaf(pv[6], u1.z, s);  s = fmaf(pv[7], u1.w, s);
        s = fmaf(pv[8], u2.x, s);  s = fmaf(pv[9], u2.y, s);
        s = fmaf(pv[10], u2.z, s); s = fmaf(pv[11], u2.w, s);
        lds[w * 65 + cg * 8 + j] = s;
    }
    __syncthreads();

    const float* w1v = w1 + 128 * 64 + cg * 8 * 64;
    float acc[8];
#pragma unroll
    for (int j = 0; j < 8; ++j) acc[j] = b1[128 + cg * 8 + j];
    for (int c2 = 0; c2 < 64; ++c2) {
        const float xv = lds[w * 65 + c2];
#pragma unroll
        for (int j = 0; j < 8; ++j)
            acc[j] = fmaf(w1v[j * 64 + c2], xv, acc[j]);
    }

#pragma unroll
    for (int j = 0; j < 8; ++j) {
        const int co = cg * 8 + j;
        float4 f; f.x = acc[j]; f.y = acc[j]; f.z = acc[j]; f.w = acc[j];
        float* op = out + ((size_t)(b * 64 + co) * 4096 + h * 64 + w) * 12;
        *(float4*)(op)     = f;
        *(float4*)(op + 4) = f;
        *(float4*)(op + 8) = f;
    }
}

// ---------------------------------------------------------------------------
extern "C" void kernel_launch(void* const* d_in, const int* in_sizes, int n_in,
                              void* d_out, int out_size, void* d_ws, size_t ws_size,
                              hipStream_t stream) {
    const float* x  = (const float*)d_in[0];
    const float* w1 = (const float*)d_in[1];
    const float* b1 = (const float*)d_in[2];
    const float* w2 = (const float*)d_in[3];
    // d_in[4] = b2: constant across the softmax axis -> cancels, unused.

    float* outp = (float*)d_out;
    float* u    = outp + U_OFF;      // 31.4 MB partial planes (scratch in d_out)
    float* p    = (float*)d_ws;      // 1.57 MB

    const bool ws_fits = ws_size >= (size_t)(WS_WEFF_OFF + 1600) * sizeof(float);
    float* weff = ws_fits ? (p + WS_WEFF_OFF) : (outp + WEFF_FALLBACK_OFF);

    hipLaunchKernelGGL(k_prep,   dim3(7),    dim3(256), 0, stream, w1, w2, weff);
    hipLaunchKernelGGL(k_tap,    dim3(1536), dim3(256), 0, stream, x, weff, u);
    hipLaunchKernelGGL(k_gather, dim3(512),  dim3(256), 0, stream, u, p);
    hipLaunchKernelGGL(k_out,    dim3(512),  dim3(512), 0, stream, x, w1, b1, p, outp);
}